// Round 12
// baseline (246.804 us; speedup 1.0000x reference)
//
#include <hip/hip_runtime.h>

#define D_MODEL 768
#define D_STATE 16
#define D_INNER 1536
#define DT_RANK 48
#define NB 2
#define LSEQ 1024
#define NROWS (NB * LSEQ)
#define CCH 8                  // chunks over L
#define CLEN (LSEQ / CCH)      // 128 steps per chunk
#define BETA_CL 1.3900845e-06f // 0.9^128

typedef __attribute__((ext_vector_type(4))) float f32x4;
typedef __attribute__((ext_vector_type(8))) short s16x8;
typedef __attribute__((ext_vector_type(8))) unsigned short u16x8;

__device__ __forceinline__ unsigned short f2bu(float f) {
  unsigned int x = __builtin_bit_cast(unsigned int, f);
  x += 0x7fffu + ((x >> 16) & 1u);
  return (unsigned short)(x >> 16);
}
__device__ __forceinline__ float bfu(unsigned short u) {
  unsigned int x = ((unsigned int)u) << 16;
  return __builtin_bit_cast(float, x);
}

// ---- one-shot: cvt 5 static operands to bf16 + zero split-K atomic targets ----
#define CVT_TOTAL 663552
#define Z1_GROUPS 20480   // xdbl: 163840 floats
#define Z2_GROUPS 196608  // d_out: 1572864 floats
__global__ __launch_bounds__(256) void cvt5z_kernel(const float* __restrict__ s0,
                                                    const float* __restrict__ s1,
                                                    const float* __restrict__ s2,
                                                    const float* __restrict__ s3,
                                                    const float* __restrict__ s4,
                                                    unsigned short* __restrict__ d0,
                                                    unsigned short* __restrict__ d1,
                                                    unsigned short* __restrict__ d2,
                                                    unsigned short* __restrict__ d3,
                                                    unsigned short* __restrict__ d4,
                                                    float* __restrict__ z1,
                                                    float* __restrict__ z2) {
  int g = blockIdx.x * 256 + threadIdx.x;
  if (g >= CVT_TOTAL) {
    int zg = g - CVT_TOTAL;
    f32x4 zero = {0.f, 0.f, 0.f, 0.f};
    if (zg < Z1_GROUPS) {
      *(f32x4*)(z1 + zg * 8) = zero;
      *(f32x4*)(z1 + zg * 8 + 4) = zero;
    } else if (zg < Z1_GROUPS + Z2_GROUPS) {
      int i = (zg - Z1_GROUPS) * 8;
      *(f32x4*)(z2 + i) = zero;
      *(f32x4*)(z2 + i + 4) = zero;
    }
    return;
  }
  const float* s;
  unsigned short* d;
  int base;
  if (g < 196608)      { s = s0; d = d0; base = 0; }
  else if (g < 491520) { s = s1; d = d1; base = 196608; }
  else if (g < 506880) { s = s2; d = d2; base = 491520; }
  else if (g < 516096) { s = s3; d = d3; base = 506880; }
  else                 { s = s4; d = d4; base = 516096; }
  int i = (g - base) * 8;
  f32x4 a = *(const f32x4*)(s + i);
  f32x4 b = *(const f32x4*)(s + i + 4);
  u16x8 o;
#pragma unroll
  for (int j = 0; j < 4; j++) { o[j] = f2bu(a[j]); o[4 + j] = f2bu(b[j]); }
  *(u16x8*)(d + i) = o;
}

// ---- 128x128 GEMM, bf16 in, fp32 accum. REQUIRES M%128==0, N%128==0, kseg%32==0 ----
template <bool ATOMIC>
__global__ __launch_bounds__(256) void gemm128(const unsigned short* __restrict__ A,
                                               const unsigned short* __restrict__ B,
                                               float* __restrict__ C, int K,
                                               int lda, int ldb, int ldc, int kseg_len) {
  __shared__ __align__(16) unsigned short As[2][128][40];
  __shared__ __align__(16) unsigned short Bs[2][128][40];
  const int m0 = blockIdx.y * 128, n0 = blockIdx.x * 128;
  const int kbeg = blockIdx.z * kseg_len;
  const int kend = kbeg + kseg_len;
  const int t = threadIdx.x;
  const int wave = t >> 6, lane = t & 63;
  const int wm = wave >> 1, wn = wave & 1;
  const int quad = lane >> 4, l16 = lane & 15;
  const int arow = t >> 1, kh = (t & 1) * 16;
  const unsigned short* Ap = A + (size_t)(m0 + arow) * lda + kh;
  const unsigned short* Bp = B + (size_t)(n0 + arow) * ldb + kh;

  u16x8 ra0, ra1, rb0, rb1;
  auto pref = [&](int k0) {
    ra0 = *(const u16x8*)(Ap + k0);
    ra1 = *(const u16x8*)(Ap + k0 + 8);
    rb0 = *(const u16x8*)(Bp + k0);
    rb1 = *(const u16x8*)(Bp + k0 + 8);
  };
  auto tolds = [&](int bi) {
    *(u16x8*)&As[bi][arow][kh] = ra0;
    *(u16x8*)&As[bi][arow][kh + 8] = ra1;
    *(u16x8*)&Bs[bi][arow][kh] = rb0;
    *(u16x8*)&Bs[bi][arow][kh + 8] = rb1;
  };

  f32x4 acc[4][4] = {};
  pref(kbeg);
  tolds(0);
  __syncthreads();
  int buf = 0;
  for (int k0 = kbeg; k0 < kend; k0 += 32) {
    const bool more = (k0 + 32 < kend);
    if (more) pref(k0 + 32);
    s16x8 af[4], bf[4];
#pragma unroll
    for (int i = 0; i < 4; i++) {
      af[i] = *(const s16x8*)&As[buf][wm * 64 + i * 16 + l16][quad * 8];
      bf[i] = *(const s16x8*)&Bs[buf][wn * 64 + i * 16 + l16][quad * 8];
    }
#pragma unroll
    for (int mi = 0; mi < 4; mi++)
#pragma unroll
      for (int ni = 0; ni < 4; ni++)
        acc[mi][ni] = __builtin_amdgcn_mfma_f32_16x16x32_bf16(af[mi], bf[ni], acc[mi][ni], 0, 0, 0);
    if (more) tolds(buf ^ 1);
    __syncthreads();
    buf ^= 1;
  }
#pragma unroll
  for (int mi = 0; mi < 4; mi++)
#pragma unroll
    for (int ni = 0; ni < 4; ni++)
#pragma unroll
      for (int r = 0; r < 4; r++) {
        int row = m0 + wm * 64 + mi * 16 + quad * 4 + r;
        int col = n0 + wn * 64 + ni * 16 + l16;
        if constexpr (ATOMIC)
          atomicAdd(&C[(size_t)row * ldc + col], acc[mi][ni][r]);
        else
          C[(size_t)row * ldc + col] = acc[mi][ni][r];
      }
}

// ---- 64x64 GEMM (bounds-checked) for x_proj ----
template <bool ATOMIC>
__global__ __launch_bounds__(256) void gemm_bt(const unsigned short* __restrict__ Ab,
                                               const unsigned short* __restrict__ B,
                                               float* __restrict__ C, int M, int N, int K,
                                               int lda, int ldb, int ldc, int kseg_len) {
  __shared__ __align__(16) unsigned short As[2][64][40];
  __shared__ __align__(16) unsigned short Bs[2][64][40];
  const int m0 = blockIdx.y * 64, n0 = blockIdx.x * 64;
  const int kbeg = blockIdx.z * kseg_len;
  const int kend = (kbeg + kseg_len < K) ? (kbeg + kseg_len) : K;
  const int t = threadIdx.x;
  const int wave = t >> 6, lane = t & 63;
  const int wm = wave >> 1, wn = wave & 1;
  const int quad = lane >> 4, l16 = lane & 15;
  const int srow = t >> 2;
  const int kseg = (t & 3) * 8;
  const bool va = (m0 + srow) < M, vb = (n0 + srow) < N;
  const unsigned short* Bp = B + (size_t)(n0 + srow) * ldb;

  u16x8 rab, rbb;
  auto pref = [&](int k0) {
    const int kk = k0 + kseg;
    const int krem = kend - kk;
    const unsigned short* Ap = Ab + (size_t)(m0 + srow) * lda + kk;
    if (va && krem >= 8) {
      rab = *(const u16x8*)Ap;
    } else {
#pragma unroll
      for (int j = 0; j < 8; j++) rab[j] = (va && j < krem) ? Ap[j] : (unsigned short)0;
    }
    if (vb && krem >= 8) {
      rbb = *(const u16x8*)(Bp + kk);
    } else {
#pragma unroll
      for (int j = 0; j < 8; j++) rbb[j] = (vb && j < krem) ? Bp[kk + j] : (unsigned short)0;
    }
  };
  auto tolds = [&](int bi) {
    *(u16x8*)&As[bi][srow][kseg] = rab;
    *(u16x8*)&Bs[bi][srow][kseg] = rbb;
  };

  f32x4 acc[2][2] = {};
  pref(kbeg);
  tolds(0);
  __syncthreads();
  int buf = 0;
  for (int k0 = kbeg; k0 < kend; k0 += 32) {
    const bool more = (k0 + 32 < kend);
    if (more) pref(k0 + 32);
    s16x8 a0 = *(const s16x8*)&As[buf][wm * 32 + l16][quad * 8];
    s16x8 a1 = *(const s16x8*)&As[buf][wm * 32 + 16 + l16][quad * 8];
    s16x8 b0 = *(const s16x8*)&Bs[buf][wn * 32 + l16][quad * 8];
    s16x8 b1 = *(const s16x8*)&Bs[buf][wn * 32 + 16 + l16][quad * 8];
    acc[0][0] = __builtin_amdgcn_mfma_f32_16x16x32_bf16(a0, b0, acc[0][0], 0, 0, 0);
    acc[0][1] = __builtin_amdgcn_mfma_f32_16x16x32_bf16(a0, b1, acc[0][1], 0, 0, 0);
    acc[1][0] = __builtin_amdgcn_mfma_f32_16x16x32_bf16(a1, b0, acc[1][0], 0, 0, 0);
    acc[1][1] = __builtin_amdgcn_mfma_f32_16x16x32_bf16(a1, b1, acc[1][1], 0, 0, 0);
    if (more) tolds(buf ^ 1);
    __syncthreads();
    buf ^= 1;
  }
#pragma unroll
  for (int mi = 0; mi < 2; mi++)
#pragma unroll
    for (int ni = 0; ni < 2; ni++)
#pragma unroll
      for (int r = 0; r < 4; r++) {
        int row = m0 + wm * 32 + mi * 16 + quad * 4 + r;
        int col = n0 + wn * 32 + ni * 16 + l16;
        if (row < M && col < N) {
          if constexpr (ATOMIC)
            atomicAdd(&C[(size_t)row * ldc + col], acc[mi][ni][r]);
          else
            C[(size_t)row * ldc + col] = acc[mi][ni][r];
        }
      }
}

// ---- causal depthwise conv (width 4) + SiLU; emits fp32 + bf16 copies ----
__global__ __launch_bounds__(256) void conv_silu_kernel(const float* __restrict__ xz,
                                                        const float* __restrict__ cw,
                                                        const float* __restrict__ cb,
                                                        float* __restrict__ xc,
                                                        unsigned short* __restrict__ xcb) {
  int idx = blockIdx.x * 256 + threadIdx.x;
  if (idx >= NROWS * D_INNER) return;
  int c = idx % D_INNER;
  int row = idx / D_INNER;
  int l = row & (LSEQ - 1);
  float acc = cb[c];
#pragma unroll
  for (int j = 0; j < 4; j++) {
    int dl = l - 3 + j;
    if (dl >= 0) acc += xz[(size_t)(row - 3 + j) * 3072 + c] * cw[c * 4 + j];
  }
  float sg = 1.0f / (1.0f + expf(-acc));
  float val = acc * sg;
  xc[idx] = val;
  xcb[idx] = f2bu(val);
}

// ---- fused dt_head + precompute: per (b,l) row ----
// dt_raw_d = dot48(xdbl[row][0:48], wdt[d]); then dt transform, gamma, u'
__global__ __launch_bounds__(256) void precompute_kernel(const float* __restrict__ xdbl,
                                                         const unsigned short* __restrict__ wdt,
                                                         const float* __restrict__ xconv,
                                                         const float* __restrict__ dtb,
                                                         float* __restrict__ dtbuf,
                                                         float* __restrict__ ubuf,
                                                         float* __restrict__ kqbuf) {
  int row = blockIdx.x;
  int t = threadIdx.x;
  __shared__ float xr_s[80];
  if (t < 80) xr_s[t] = xdbl[(size_t)row * 80 + t];
  __syncthreads();
  float nk = 0.0f;
#pragma unroll
  for (int n = 0; n < 16; n++) { float kv = xr_s[48 + n]; nk += kv * kv; }
  float dtf[6], u0[6];
  float nupart = 0.0f;
#pragma unroll
  for (int i = 0; i < 6; i++) {
    int d = i * 256 + t;
    // dt_head dot: 48 MACs against bf16 W_dt (L2-resident, 144 KB)
    float draw = dtb[d];
    const unsigned short* w = wdt + (size_t)d * 48;
#pragma unroll
    for (int j = 0; j < 6; j++) {
      u16x8 wv = *(const u16x8*)(w + j * 8);
#pragma unroll
      for (int e = 0; e < 8; e++) draw = fmaf(bfu(wv[e]), xr_s[j * 8 + e], draw);
    }
    float sg = 1.0f / (1.0f + expf(-draw));
    float dv = sg / (1.0f + sg * nk);
    dtf[i] = dv;
    float u = dv * xconv[(size_t)row * D_INNER + d];
    u0[i] = u;
    nupart += u * u;
  }
  __shared__ float red[4];
  float v = nupart;
#pragma unroll
  for (int off = 32; off > 0; off >>= 1) v += __shfl_xor(v, off);
  if ((t & 63) == 0) red[t >> 6] = v;
  __syncthreads();
  float nu = red[0] + red[1] + red[2] + red[3];
  float p = nu * nk;
  float s = sqrtf(p) + 1e-7f;
  float tt = p / (s * s);
  float gamma = (3.4445f + tt * (-4.7750f + 2.0315f * tt)) / s;
#pragma unroll
  for (int i = 0; i < 6; i++) {
    int d = i * 256 + t;
    dtbuf[(size_t)row * D_INNER + d] = dtf[i];
    ubuf[(size_t)row * D_INNER + d] = gamma * u0[i];
  }
  if (t < 16) {
    kqbuf[(size_t)row * 32 + t] = xr_s[48 + t];       // k
    kqbuf[(size_t)row * 32 + 16 + t] = xr_s[64 + t];  // q
  }
}

// ================= segmented scan =================
__global__ __launch_bounds__(64) void scan_phase1(const float* __restrict__ ubuf,
                                                  const float* __restrict__ dtbuf,
                                                  const float* __restrict__ kqbuf,
                                                  float* __restrict__ cvp,
                                                  float* __restrict__ chp,
                                                  float* __restrict__ gp,
                                                  float* __restrict__ rp) {
  __shared__ float u_s[2][32][16];
  __shared__ float dt_s[2][32][16];
  __shared__ __align__(16) float kq_s[2][32][32];
  const int t = threadIdx.x;
  const int nq = t & 3, dloc = t >> 2;
  const int b = blockIdx.x / (96 * CCH);
  const int rem = blockIdx.x % (96 * CCH);
  const int d0 = (rem / CCH) * 16;
  const int c = rem % CCH;
  const int tbase = c * CLEN;
  const size_t ub = (size_t)b * LSEQ * D_INNER + d0;
  const float* kqb = kqbuf + (size_t)b * LSEQ * 32;
  const int scol = t & 15, srow0 = t >> 4;
  const int krow0 = t >> 3, kcol = (t & 7) * 4;
  float pu[8], pd[8];
  f32x4 pk[4];
  auto prefetch = [&](int t0) {
#pragma unroll
    for (int i = 0; i < 8; i++) {
      size_t off = ub + (size_t)(t0 + srow0 + 4 * i) * D_INNER + scol;
      pu[i] = ubuf[off];
      pd[i] = dtbuf[off];
    }
#pragma unroll
    for (int i = 0; i < 4; i++)
      pk[i] = *(const f32x4*)(kqb + (size_t)(t0 + krow0 + 8 * i) * 32 + kcol);
  };
  auto writelds = [&](int bi) {
#pragma unroll
    for (int i = 0; i < 8; i++) {
      u_s[bi][srow0 + 4 * i][scol] = pu[i];
      dt_s[bi][srow0 + 4 * i][scol] = pd[i];
    }
#pragma unroll
    for (int i = 0; i < 4; i++)
      *(f32x4*)&kq_s[bi][krow0 + 8 * i][kcol] = pk[i];
  };
  f32x4 v = {0.f, 0.f, 0.f, 0.f}, h = {0.f, 0.f, 0.f, 0.f};
  f32x4 g = {0.f, 0.f, 0.f, 0.f}, r = {1.f, 1.f, 1.f, 1.f};
  float bt = 0.9f;
  prefetch(tbase);
  writelds(0);
  int buf = 0;
  for (int t0 = 0; t0 < CLEN; t0 += 32) {
    const bool more = (t0 + 32 < CLEN);
    if (more) prefetch(tbase + t0 + 32);
#pragma unroll 4
    for (int s = 0; s < 32; s++) {
      float u = u_s[buf][s][dloc];
      float dtf = dt_s[buf][s][dloc];
      f32x4 kv = *(const f32x4*)&kq_s[buf][s][nq * 4];
#pragma unroll
      for (int j = 0; j < 4; j++) {
        float kj = kv[j];
        v[j] = fmaf(0.9f, v[j], u * kj);
        float a = fmaf(-dtf * kj, kj, 1.0f);
        h[j] = fmaf(a, h[j], v[j]);
        r[j] *= a;
        g[j] = fmaf(a, g[j], bt);
      }
      bt *= 0.9f;
    }
    if (more) writelds(buf ^ 1);
    buf ^= 1;
  }
  size_t o = (((size_t)b * CCH + c) * D_INNER + d0 + dloc) * 16 + nq * 4;
  *(f32x4*)(cvp + o) = v;
  *(f32x4*)(chp + o) = h;
  *(f32x4*)(gp + o) = g;
  *(f32x4*)(rp + o) = r;
}

__global__ __launch_bounds__(256) void scan_phase2(const float* __restrict__ cvp,
                                                   const float* __restrict__ chp,
                                                   float* __restrict__ gp,
                                                   float* __restrict__ rp) {
  int i = blockIdx.x * 256 + threadIdx.x;  // 49152 = 2*1536*16
  int b = i / (D_INNER * 16);
  int rem = i % (D_INNER * 16);
  float v0 = 0.f, h0 = 0.f;
#pragma unroll
  for (int c = 0; c < CCH; c++) {
    size_t o = ((size_t)(b * CCH + c)) * (D_INNER * 16) + rem;
    float cv = cvp[o], ch = chp[o], gg = gp[o], rr = rp[o];
    gp[o] = v0;
    rp[o] = h0;
    float v0n = fmaf(BETA_CL, v0, cv);
    float h0n = fmaf(gg, v0, fmaf(rr, h0, ch));
    v0 = v0n;
    h0 = h0n;
  }
}

// phase 3 + fused gate: emit ygb = bf16((y + D*xconv) * silu(z)) directly
__global__ __launch_bounds__(64) void scan_phase3(const float* __restrict__ ubuf,
                                                  const float* __restrict__ dtbuf,
                                                  const float* __restrict__ kqbuf,
                                                  const float* __restrict__ gp,
                                                  const float* __restrict__ rp,
                                                  const float* __restrict__ xconv,
                                                  const float* __restrict__ xz,
                                                  const float* __restrict__ Dp,
                                                  unsigned short* __restrict__ ygb) {
  __shared__ float u_s[2][32][16];
  __shared__ float dt_s[2][32][16];
  __shared__ float xc_s[2][32][16];
  __shared__ float z_s[2][32][16];
  __shared__ __align__(16) float kq_s[2][32][32];
  const int t = threadIdx.x;
  const int nq = t & 3, dloc = t >> 2;
  const int b = blockIdx.x / (96 * CCH);
  const int rem = blockIdx.x % (96 * CCH);
  const int d0 = (rem / CCH) * 16;
  const int c = rem % CCH;
  const int tbase = c * CLEN;
  const size_t ub = (size_t)b * LSEQ * D_INNER + d0;
  const float* kqb = kqbuf + (size_t)b * LSEQ * 32;
  unsigned short* y_p = ygb + (size_t)b * LSEQ * D_INNER + d0 + dloc;
  const float Dd = Dp[d0 + dloc];
  const int scol = t & 15, srow0 = t >> 4;
  const int krow0 = t >> 3, kcol = (t & 7) * 4;
  float pu[8], pd[8], pxc[8], pz[8];
  f32x4 pk[4];
  auto prefetch = [&](int t0) {
#pragma unroll
    for (int i = 0; i < 8; i++) {
      int lrow = t0 + srow0 + 4 * i;
      size_t off = ub + (size_t)lrow * D_INNER + scol;
      pu[i] = ubuf[off];
      pd[i] = dtbuf[off];
      pxc[i] = xconv[off];
      pz[i] = xz[((size_t)b * LSEQ + lrow) * 3072 + 1536 + d0 + scol];
    }
#pragma unroll
    for (int i = 0; i < 4; i++)
      pk[i] = *(const f32x4*)(kqb + (size_t)(t0 + krow0 + 8 * i) * 32 + kcol);
  };
  auto writelds = [&](int bi) {
#pragma unroll
    for (int i = 0; i < 8; i++) {
      u_s[bi][srow0 + 4 * i][scol] = pu[i];
      dt_s[bi][srow0 + 4 * i][scol] = pd[i];
      xc_s[bi][srow0 + 4 * i][scol] = pxc[i];
      z_s[bi][srow0 + 4 * i][scol] = pz[i];
    }
#pragma unroll
    for (int i = 0; i < 4; i++)
      *(f32x4*)&kq_s[bi][krow0 + 8 * i][kcol] = pk[i];
  };
  size_t so = (((size_t)b * CCH + c) * D_INNER + d0 + dloc) * 16 + nq * 4;
  f32x4 v = *(const f32x4*)(gp + so);
  f32x4 h = *(const f32x4*)(rp + so);
  prefetch(tbase);
  writelds(0);
  int buf = 0;
  for (int t0 = 0; t0 < CLEN; t0 += 32) {
    const bool more = (t0 + 32 < CLEN);
    if (more) prefetch(tbase + t0 + 32);
#pragma unroll 4
    for (int s = 0; s < 32; s++) {
      float u = u_s[buf][s][dloc];
      float dtf = dt_s[buf][s][dloc];
      f32x4 kv = *(const f32x4*)&kq_s[buf][s][nq * 4];
      f32x4 qv = *(const f32x4*)&kq_s[buf][s][16 + nq * 4];
      float yp = 0.0f;
#pragma unroll
      for (int j = 0; j < 4; j++) {
        float kj = kv[j];
        v[j] = fmaf(0.9f, v[j], u * kj);
        float dA = fmaf(-dtf * kj, kj, 1.0f);
        h[j] = fmaf(dA, h[j], v[j]);
        yp = fmaf(h[j], qv[j], yp);
      }
      yp += __shfl_xor(yp, 1);
      yp += __shfl_xor(yp, 2);
      if (nq == 0) {
        float z = z_s[buf][s][dloc];
        float sz = z / (1.0f + expf(-z));
        float val = (yp + Dd * xc_s[buf][s][dloc]) * sz;
        y_p[(size_t)(tbase + t0 + s) * D_INNER] = f2bu(val);
      }
    }
    if (more) writelds(buf ^ 1);
    buf ^= 1;
  }
}

extern "C" void kernel_launch(void* const* d_in, const int* in_sizes, int n_in,
                              void* d_out, int out_size, void* d_ws, size_t ws_size,
                              hipStream_t stream) {
  const float* hidden = (const float*)d_in[0];
  const float* w_in   = (const float*)d_in[1];
  const float* conv_w = (const float*)d_in[2];
  const float* conv_b = (const float*)d_in[3];
  const float* w_x    = (const float*)d_in[4];
  const float* w_dt   = (const float*)d_in[5];
  const float* b_dt   = (const float*)d_in[6];
  const float* w_out  = (const float*)d_in[7];
  const float* Dp     = (const float*)d_in[8];

  float* ws    = (float*)d_ws;
  float* xz    = ws;                                  // 2048*3072
  float* xconv = xz + (size_t)NROWS * 3072;           // 2048*1536
  float* xdbl  = xconv + (size_t)NROWS * D_INNER;     // 2048*80
  float* dtbuf = xdbl + (size_t)NROWS * 80;           // 2048*1536
  float* ubuf  = dtbuf + (size_t)NROWS * D_INNER;     // 2048*1536
  float* kqbuf = ubuf + (size_t)NROWS * D_INNER;      // 2048*32
  float* ybuf  = kqbuf + (size_t)NROWS * 32;          // (unused, kept for layout)
  const size_t PL = (size_t)NB * CCH * D_INNER * 16;  // 393216 per plane
  float* cvp   = ybuf + (size_t)NROWS * D_INNER;
  float* chp   = cvp + PL;
  float* gp    = chp + PL;
  float* rp    = gp + PL;
  unsigned short* bfr = (unsigned short*)(rp + PL);
  unsigned short* hbf = bfr;                          // 1572864
  unsigned short* wib = hbf + 1572864;                // 2359296
  unsigned short* wxb = wib + 2359296;                // 122880
  unsigned short* wdb = wxb + 122880;                 // 73728
  unsigned short* wob = wdb + 73728;                  // 1179648
  unsigned short* xcb = wob + 1179648;                // 3145728
  unsigned short* ygb = xcb + 3145728;                // 3145728

  dim3 blk(256);
  // 0. cvt static operands to bf16 + zero xdbl/d_out (split-K atomic targets)
  cvt5z_kernel<<<dim3((CVT_TOTAL + Z1_GROUPS + Z2_GROUPS) / 256), blk, 0, stream>>>(
      hidden, w_in, w_x, w_dt, w_out, hbf, wib, wxb, wdb, wob, xdbl, (float*)d_out);
  // 1. in_proj: 128x128 tile (2048 x 3072, K=768)
  gemm128<false><<<dim3(24, 16, 1), blk, 0, stream>>>(hbf, wib, xz, 768, 768, 768, 3072, 768);
  // 2. causal conv + SiLU (fp32 + bf16 outputs)
  conv_silu_kernel<<<dim3(12288), blk, 0, stream>>>(xz, conv_w, conv_b, xconv, xcb);
  // 3. x_proj: 64-tile split-K=8, atomic (2048 x 80, K=1536)
  gemm_bt<true><<<dim3(2, 32, 8), blk, 0, stream>>>(xcb, wxb, xdbl, 2048, 80, 1536,
                                                    1536, 1536, 80, 192);
  // 4. precompute (+ fused dt_head dot48)
  precompute_kernel<<<dim3(NROWS), blk, 0, stream>>>(xdbl, wdb, xconv, b_dt, dtbuf, ubuf, kqbuf);
  // 5. segmented scan: ph1, ph2, ph3(+gate -> bf16 ygb)
  scan_phase1<<<dim3(NB * 96 * CCH), dim3(64), 0, stream>>>(ubuf, dtbuf, kqbuf, cvp, chp, gp, rp);
  scan_phase2<<<dim3(192), blk, 0, stream>>>(cvp, chp, gp, rp);
  scan_phase3<<<dim3(NB * 96 * CCH), dim3(64), 0, stream>>>(ubuf, dtbuf, kqbuf, gp, rp,
                                                            xconv, xz, Dp, ygb);
  // 6. out_proj: 128x128 split-K=4, atomic -> FP32 d_out (2048 x 768, K=1536)
  gemm128<true><<<dim3(6, 16, 4), blk, 0, stream>>>(ygb, wob, (float*)d_out, 384,
                                                    1536, 1536, 768, 384);
}

// Round 13
// 241.012 us; speedup vs baseline: 1.0240x; 1.0240x over previous
//
#include <hip/hip_runtime.h>

#define D_MODEL 768
#define D_STATE 16
#define D_INNER 1536
#define DT_RANK 48
#define NB 2
#define LSEQ 1024
#define NROWS (NB * LSEQ)
#define CCH 8                  // chunks over L
#define CLEN (LSEQ / CCH)      // 128 steps per chunk
#define BETA_CL 1.3900845e-06f // 0.9^128

typedef __attribute__((ext_vector_type(4))) float f32x4;
typedef __attribute__((ext_vector_type(8))) short s16x8;
typedef __attribute__((ext_vector_type(8))) unsigned short u16x8;

__device__ __forceinline__ unsigned short f2bu(float f) {
  unsigned int x = __builtin_bit_cast(unsigned int, f);
  x += 0x7fffu + ((x >> 16) & 1u);
  return (unsigned short)(x >> 16);
}
__device__ __forceinline__ float bfu(unsigned short u) {
  unsigned int x = ((unsigned int)u) << 16;
  return __builtin_bit_cast(float, x);
}

// ---- one-shot: cvt 5 static operands to bf16 + zero split-K atomic targets ----
#define CVT_TOTAL 663552
#define Z1_GROUPS 20480   // xdbl: 163840 floats
#define Z2_GROUPS 196608  // d_out: 1572864 floats
__global__ __launch_bounds__(256) void cvt5z_kernel(const float* __restrict__ s0,
                                                    const float* __restrict__ s1,
                                                    const float* __restrict__ s2,
                                                    const float* __restrict__ s3,
                                                    const float* __restrict__ s4,
                                                    unsigned short* __restrict__ d0,
                                                    unsigned short* __restrict__ d1,
                                                    unsigned short* __restrict__ d2,
                                                    unsigned short* __restrict__ d3,
                                                    unsigned short* __restrict__ d4,
                                                    float* __restrict__ z1,
                                                    float* __restrict__ z2) {
  int g = blockIdx.x * 256 + threadIdx.x;
  if (g >= CVT_TOTAL) {
    int zg = g - CVT_TOTAL;
    f32x4 zero = {0.f, 0.f, 0.f, 0.f};
    if (zg < Z1_GROUPS) {
      *(f32x4*)(z1 + zg * 8) = zero;
      *(f32x4*)(z1 + zg * 8 + 4) = zero;
    } else if (zg < Z1_GROUPS + Z2_GROUPS) {
      int i = (zg - Z1_GROUPS) * 8;
      *(f32x4*)(z2 + i) = zero;
      *(f32x4*)(z2 + i + 4) = zero;
    }
    return;
  }
  const float* s;
  unsigned short* d;
  int base;
  if (g < 196608)      { s = s0; d = d0; base = 0; }
  else if (g < 491520) { s = s1; d = d1; base = 196608; }
  else if (g < 506880) { s = s2; d = d2; base = 491520; }
  else if (g < 516096) { s = s3; d = d3; base = 506880; }
  else                 { s = s4; d = d4; base = 516096; }
  int i = (g - base) * 8;
  f32x4 a = *(const f32x4*)(s + i);
  f32x4 b = *(const f32x4*)(s + i + 4);
  u16x8 o;
#pragma unroll
  for (int j = 0; j < 4; j++) { o[j] = f2bu(a[j]); o[4 + j] = f2bu(b[j]); }
  *(u16x8*)(d + i) = o;
}

// ---- 128x128 GEMM, bf16 in, fp32 accum. REQUIRES M%128==0, N%128==0, kseg%32==0 ----
template <bool ATOMIC>
__global__ __launch_bounds__(256) void gemm128(const unsigned short* __restrict__ A,
                                               const unsigned short* __restrict__ B,
                                               float* __restrict__ C, int K,
                                               int lda, int ldb, int ldc, int kseg_len) {
  __shared__ __align__(16) unsigned short As[2][128][40];
  __shared__ __align__(16) unsigned short Bs[2][128][40];
  const int m0 = blockIdx.y * 128, n0 = blockIdx.x * 128;
  const int kbeg = blockIdx.z * kseg_len;
  const int kend = kbeg + kseg_len;
  const int t = threadIdx.x;
  const int wave = t >> 6, lane = t & 63;
  const int wm = wave >> 1, wn = wave & 1;
  const int quad = lane >> 4, l16 = lane & 15;
  const int arow = t >> 1, kh = (t & 1) * 16;
  const unsigned short* Ap = A + (size_t)(m0 + arow) * lda + kh;
  const unsigned short* Bp = B + (size_t)(n0 + arow) * ldb + kh;

  u16x8 ra0, ra1, rb0, rb1;
  auto pref = [&](int k0) {
    ra0 = *(const u16x8*)(Ap + k0);
    ra1 = *(const u16x8*)(Ap + k0 + 8);
    rb0 = *(const u16x8*)(Bp + k0);
    rb1 = *(const u16x8*)(Bp + k0 + 8);
  };
  auto tolds = [&](int bi) {
    *(u16x8*)&As[bi][arow][kh] = ra0;
    *(u16x8*)&As[bi][arow][kh + 8] = ra1;
    *(u16x8*)&Bs[bi][arow][kh] = rb0;
    *(u16x8*)&Bs[bi][arow][kh + 8] = rb1;
  };

  f32x4 acc[4][4] = {};
  pref(kbeg);
  tolds(0);
  __syncthreads();
  int buf = 0;
  for (int k0 = kbeg; k0 < kend; k0 += 32) {
    const bool more = (k0 + 32 < kend);
    if (more) pref(k0 + 32);
    s16x8 af[4], bf[4];
#pragma unroll
    for (int i = 0; i < 4; i++) {
      af[i] = *(const s16x8*)&As[buf][wm * 64 + i * 16 + l16][quad * 8];
      bf[i] = *(const s16x8*)&Bs[buf][wn * 64 + i * 16 + l16][quad * 8];
    }
#pragma unroll
    for (int mi = 0; mi < 4; mi++)
#pragma unroll
      for (int ni = 0; ni < 4; ni++)
        acc[mi][ni] = __builtin_amdgcn_mfma_f32_16x16x32_bf16(af[mi], bf[ni], acc[mi][ni], 0, 0, 0);
    if (more) tolds(buf ^ 1);
    __syncthreads();
    buf ^= 1;
  }
#pragma unroll
  for (int mi = 0; mi < 4; mi++)
#pragma unroll
    for (int ni = 0; ni < 4; ni++)
#pragma unroll
      for (int r = 0; r < 4; r++) {
        int row = m0 + wm * 64 + mi * 16 + quad * 4 + r;
        int col = n0 + wn * 64 + ni * 16 + l16;
        if constexpr (ATOMIC)
          atomicAdd(&C[(size_t)row * ldc + col], acc[mi][ni][r]);
        else
          C[(size_t)row * ldc + col] = acc[mi][ni][r];
      }
}

// ---- 64x64 GEMM (bounds-checked) for x_proj ----
template <bool ATOMIC>
__global__ __launch_bounds__(256) void gemm_bt(const unsigned short* __restrict__ Ab,
                                               const unsigned short* __restrict__ B,
                                               float* __restrict__ C, int M, int N, int K,
                                               int lda, int ldb, int ldc, int kseg_len) {
  __shared__ __align__(16) unsigned short As[2][64][40];
  __shared__ __align__(16) unsigned short Bs[2][64][40];
  const int m0 = blockIdx.y * 64, n0 = blockIdx.x * 64;
  const int kbeg = blockIdx.z * kseg_len;
  const int kend = (kbeg + kseg_len < K) ? (kbeg + kseg_len) : K;
  const int t = threadIdx.x;
  const int wave = t >> 6, lane = t & 63;
  const int wm = wave >> 1, wn = wave & 1;
  const int quad = lane >> 4, l16 = lane & 15;
  const int srow = t >> 2;
  const int kseg = (t & 3) * 8;
  const bool va = (m0 + srow) < M, vb = (n0 + srow) < N;
  const unsigned short* Bp = B + (size_t)(n0 + srow) * ldb;

  u16x8 rab, rbb;
  auto pref = [&](int k0) {
    const int kk = k0 + kseg;
    const int krem = kend - kk;
    const unsigned short* Ap = Ab + (size_t)(m0 + srow) * lda + kk;
    if (va && krem >= 8) {
      rab = *(const u16x8*)Ap;
    } else {
#pragma unroll
      for (int j = 0; j < 8; j++) rab[j] = (va && j < krem) ? Ap[j] : (unsigned short)0;
    }
    if (vb && krem >= 8) {
      rbb = *(const u16x8*)(Bp + kk);
    } else {
#pragma unroll
      for (int j = 0; j < 8; j++) rbb[j] = (vb && j < krem) ? Bp[kk + j] : (unsigned short)0;
    }
  };
  auto tolds = [&](int bi) {
    *(u16x8*)&As[bi][srow][kseg] = rab;
    *(u16x8*)&Bs[bi][srow][kseg] = rbb;
  };

  f32x4 acc[2][2] = {};
  pref(kbeg);
  tolds(0);
  __syncthreads();
  int buf = 0;
  for (int k0 = kbeg; k0 < kend; k0 += 32) {
    const bool more = (k0 + 32 < kend);
    if (more) pref(k0 + 32);
    s16x8 a0 = *(const s16x8*)&As[buf][wm * 32 + l16][quad * 8];
    s16x8 a1 = *(const s16x8*)&As[buf][wm * 32 + 16 + l16][quad * 8];
    s16x8 b0 = *(const s16x8*)&Bs[buf][wn * 32 + l16][quad * 8];
    s16x8 b1 = *(const s16x8*)&Bs[buf][wn * 32 + 16 + l16][quad * 8];
    acc[0][0] = __builtin_amdgcn_mfma_f32_16x16x32_bf16(a0, b0, acc[0][0], 0, 0, 0);
    acc[0][1] = __builtin_amdgcn_mfma_f32_16x16x32_bf16(a0, b1, acc[0][1], 0, 0, 0);
    acc[1][0] = __builtin_amdgcn_mfma_f32_16x16x32_bf16(a1, b0, acc[1][0], 0, 0, 0);
    acc[1][1] = __builtin_amdgcn_mfma_f32_16x16x32_bf16(a1, b1, acc[1][1], 0, 0, 0);
    if (more) tolds(buf ^ 1);
    __syncthreads();
    buf ^= 1;
  }
#pragma unroll
  for (int mi = 0; mi < 2; mi++)
#pragma unroll
    for (int ni = 0; ni < 2; ni++)
#pragma unroll
      for (int r = 0; r < 4; r++) {
        int row = m0 + wm * 32 + mi * 16 + quad * 4 + r;
        int col = n0 + wn * 32 + ni * 16 + l16;
        if (row < M && col < N) {
          if constexpr (ATOMIC)
            atomicAdd(&C[(size_t)row * ldc + col], acc[mi][ni][r]);
          else
            C[(size_t)row * ldc + col] = acc[mi][ni][r];
        }
      }
}

// ---- conv + SiLU; emits xc (linear fp32), xcb (linear bf16),
//      sz=silu(z) (BLOCKED fp32), gz=D*xc*sz (BLOCKED bf16) ----
__global__ __launch_bounds__(256) void conv_silu_kernel(const float* __restrict__ xz,
                                                        const float* __restrict__ cw,
                                                        const float* __restrict__ cb,
                                                        const float* __restrict__ Dp,
                                                        float* __restrict__ xc,
                                                        unsigned short* __restrict__ xcb,
                                                        float* __restrict__ szb,
                                                        unsigned short* __restrict__ gzb) {
  int idx = blockIdx.x * 256 + threadIdx.x;
  if (idx >= NROWS * D_INNER) return;
  int c = idx % D_INNER;
  int row = idx / D_INNER;
  int b = row >> 10;
  int l = row & (LSEQ - 1);
  float acc = cb[c];
#pragma unroll
  for (int j = 0; j < 4; j++) {
    int dl = l - 3 + j;
    if (dl >= 0) acc += xz[(size_t)(row - 3 + j) * 3072 + c] * cw[c * 4 + j];
  }
  float sg = 1.0f / (1.0f + expf(-acc));
  float val = acc * sg;
  xc[idx] = val;
  xcb[idx] = f2bu(val);
  float z = xz[(size_t)row * 3072 + 1536 + c];
  float sz = z / (1.0f + expf(-z));
  size_t bo = (((size_t)(b * 96 + (c >> 4))) * LSEQ + l) * 16 + (c & 15);
  szb[bo] = sz;
  gzb[bo] = f2bu(Dp[c] * val * sz);
}

// ---- fused dt_head + precompute; u/dt written in BLOCKED layout ----
__global__ __launch_bounds__(256) void precompute_kernel(const float* __restrict__ xdbl,
                                                         const unsigned short* __restrict__ wdt,
                                                         const float* __restrict__ xconv,
                                                         const float* __restrict__ dtb,
                                                         float* __restrict__ dtblk,
                                                         float* __restrict__ ublk,
                                                         float* __restrict__ kqbuf) {
  int row = blockIdx.x;
  int t = threadIdx.x;
  int b = row >> 10;
  int l = row & (LSEQ - 1);
  __shared__ float xr_s[80];
  if (t < 80) xr_s[t] = xdbl[(size_t)row * 80 + t];
  __syncthreads();
  float nk = 0.0f;
#pragma unroll
  for (int n = 0; n < 16; n++) { float kv = xr_s[48 + n]; nk += kv * kv; }
  float dtf[6], u0[6];
  float nupart = 0.0f;
#pragma unroll
  for (int i = 0; i < 6; i++) {
    int d = i * 256 + t;
    float draw = dtb[d];
    const unsigned short* w = wdt + (size_t)d * 48;
#pragma unroll
    for (int j = 0; j < 6; j++) {
      u16x8 wv = *(const u16x8*)(w + j * 8);
#pragma unroll
      for (int e = 0; e < 8; e++) draw = fmaf(bfu(wv[e]), xr_s[j * 8 + e], draw);
    }
    float sg = 1.0f / (1.0f + expf(-draw));
    float dv = sg / (1.0f + sg * nk);
    dtf[i] = dv;
    float u = dv * xconv[(size_t)row * D_INNER + d];
    u0[i] = u;
    nupart += u * u;
  }
  __shared__ float red[4];
  float v = nupart;
#pragma unroll
  for (int off = 32; off > 0; off >>= 1) v += __shfl_xor(v, off);
  if ((t & 63) == 0) red[t >> 6] = v;
  __syncthreads();
  float nu = red[0] + red[1] + red[2] + red[3];
  float p = nu * nk;
  float s = sqrtf(p) + 1e-7f;
  float tt = p / (s * s);
  float gamma = (3.4445f + tt * (-4.7750f + 2.0315f * tt)) / s;
#pragma unroll
  for (int i = 0; i < 6; i++) {
    int d = i * 256 + t;
    size_t bo = (((size_t)(b * 96 + (d >> 4))) * LSEQ + l) * 16 + (d & 15);
    dtblk[bo] = dtf[i];
    ublk[bo] = gamma * u0[i];
  }
  if (t < 16) {
    kqbuf[(size_t)row * 32 + t] = xr_s[48 + t];       // k
    kqbuf[(size_t)row * 32 + 16 + t] = xr_s[64 + t];  // q
  }
}

// ================= segmented scan (blocked u/dt: fully coalesced tiles) =================
__global__ __launch_bounds__(64) void scan_phase1(const float* __restrict__ ublk,
                                                  const float* __restrict__ dtblk,
                                                  const float* __restrict__ kqbuf,
                                                  float* __restrict__ cvp,
                                                  float* __restrict__ chp,
                                                  float* __restrict__ gp,
                                                  float* __restrict__ rp) {
  __shared__ float u_s[2][512];
  __shared__ float dt_s[2][512];
  __shared__ __align__(16) float kq_s[2][32][32];
  const int t = threadIdx.x;
  const int nq = t & 3, dloc = t >> 2;
  const int b = blockIdx.x / (96 * CCH);
  const int rem = blockIdx.x % (96 * CCH);
  const int db = rem / CCH;
  const int c = rem % CCH;
  const int tbase = c * CLEN;
  const float* ubp = ublk + (((size_t)(b * 96 + db)) * LSEQ + tbase) * 16;
  const float* dtp = dtblk + (((size_t)(b * 96 + db)) * LSEQ + tbase) * 16;
  const float* kqb = kqbuf + (size_t)b * LSEQ * 32;
  const int krow0 = t >> 3, kcol = (t & 7) * 4;
  f32x4 pu0, pu1, pd0, pd1, pk[4];
  auto prefetch = [&](int lt) {  // lt: local step base within chunk
    pu0 = *(const f32x4*)(ubp + lt * 16 + t * 8);
    pu1 = *(const f32x4*)(ubp + lt * 16 + t * 8 + 4);
    pd0 = *(const f32x4*)(dtp + lt * 16 + t * 8);
    pd1 = *(const f32x4*)(dtp + lt * 16 + t * 8 + 4);
#pragma unroll
    for (int i = 0; i < 4; i++)
      pk[i] = *(const f32x4*)(kqb + (size_t)(tbase + lt + krow0 + 8 * i) * 32 + kcol);
  };
  auto writelds = [&](int bi) {
    *(f32x4*)&u_s[bi][t * 8] = pu0;
    *(f32x4*)&u_s[bi][t * 8 + 4] = pu1;
    *(f32x4*)&dt_s[bi][t * 8] = pd0;
    *(f32x4*)&dt_s[bi][t * 8 + 4] = pd1;
#pragma unroll
    for (int i = 0; i < 4; i++)
      *(f32x4*)&kq_s[bi][krow0 + 8 * i][kcol] = pk[i];
  };
  f32x4 v = {0.f, 0.f, 0.f, 0.f}, h = {0.f, 0.f, 0.f, 0.f};
  f32x4 g = {0.f, 0.f, 0.f, 0.f}, r = {1.f, 1.f, 1.f, 1.f};
  float bt = 0.9f;
  prefetch(0);
  writelds(0);
  int buf = 0;
  for (int t0 = 0; t0 < CLEN; t0 += 32) {
    const bool more = (t0 + 32 < CLEN);
    if (more) prefetch(t0 + 32);
#pragma unroll 4
    for (int s = 0; s < 32; s++) {
      float u = u_s[buf][s * 16 + dloc];
      float dtf = dt_s[buf][s * 16 + dloc];
      f32x4 kv = *(const f32x4*)&kq_s[buf][s][nq * 4];
#pragma unroll
      for (int j = 0; j < 4; j++) {
        float kj = kv[j];
        v[j] = fmaf(0.9f, v[j], u * kj);
        float a = fmaf(-dtf * kj, kj, 1.0f);
        h[j] = fmaf(a, h[j], v[j]);
        r[j] *= a;
        g[j] = fmaf(a, g[j], bt);
      }
      bt *= 0.9f;
    }
    if (more) writelds(buf ^ 1);
    buf ^= 1;
  }
  size_t o = (((size_t)b * CCH + c) * D_INNER + db * 16 + dloc) * 16 + nq * 4;
  *(f32x4*)(cvp + o) = v;
  *(f32x4*)(chp + o) = h;
  *(f32x4*)(gp + o) = g;
  *(f32x4*)(rp + o) = r;
}

__global__ __launch_bounds__(256) void scan_phase2(const float* __restrict__ cvp,
                                                   const float* __restrict__ chp,
                                                   float* __restrict__ gp,
                                                   float* __restrict__ rp) {
  int i = blockIdx.x * 256 + threadIdx.x;  // 49152 = 2*1536*16
  int b = i / (D_INNER * 16);
  int rem = i % (D_INNER * 16);
  float v0 = 0.f, h0 = 0.f;
#pragma unroll
  for (int c = 0; c < CCH; c++) {
    size_t o = ((size_t)(b * CCH + c)) * (D_INNER * 16) + rem;
    float cv = cvp[o], ch = chp[o], gg = gp[o], rr = rp[o];
    gp[o] = v0;
    rp[o] = h0;
    float v0n = fmaf(BETA_CL, v0, cv);
    float h0n = fmaf(gg, v0, fmaf(rr, h0, ch));
    v0 = v0n;
    h0 = h0n;
  }
}

// phase 3 + fused gate: ygb = bf16(yp*sz + gz), sz/gz precomputed blocked
__global__ __launch_bounds__(64) void scan_phase3(const float* __restrict__ ublk,
                                                  const float* __restrict__ dtblk,
                                                  const float* __restrict__ kqbuf,
                                                  const float* __restrict__ gp,
                                                  const float* __restrict__ rp,
                                                  const float* __restrict__ szb,
                                                  const unsigned short* __restrict__ gzb,
                                                  unsigned short* __restrict__ ygb) {
  __shared__ float u_s[2][512];
  __shared__ float dt_s[2][512];
  __shared__ float sz_s[2][512];
  __shared__ unsigned short gz_s[2][512];
  __shared__ __align__(16) float kq_s[2][32][32];
  const int t = threadIdx.x;
  const int nq = t & 3, dloc = t >> 2;
  const int b = blockIdx.x / (96 * CCH);
  const int rem = blockIdx.x % (96 * CCH);
  const int db = rem / CCH;
  const int c = rem % CCH;
  const int tbase = c * CLEN;
  const size_t blkoff = (((size_t)(b * 96 + db)) * LSEQ + tbase) * 16;
  const float* ubp = ublk + blkoff;
  const float* dtp = dtblk + blkoff;
  const float* szp = szb + blkoff;
  const unsigned short* gzp = gzb + blkoff;
  const float* kqb = kqbuf + (size_t)b * LSEQ * 32;
  unsigned short* y_p = ygb + (size_t)b * LSEQ * D_INNER + db * 16 + dloc;
  const int krow0 = t >> 3, kcol = (t & 7) * 4;
  f32x4 pu0, pu1, pd0, pd1, ps0, ps1, pk[4];
  u16x8 pg;
  auto prefetch = [&](int lt) {
    pu0 = *(const f32x4*)(ubp + lt * 16 + t * 8);
    pu1 = *(const f32x4*)(ubp + lt * 16 + t * 8 + 4);
    pd0 = *(const f32x4*)(dtp + lt * 16 + t * 8);
    pd1 = *(const f32x4*)(dtp + lt * 16 + t * 8 + 4);
    ps0 = *(const f32x4*)(szp + lt * 16 + t * 8);
    ps1 = *(const f32x4*)(szp + lt * 16 + t * 8 + 4);
    pg = *(const u16x8*)(gzp + lt * 16 + t * 8);
#pragma unroll
    for (int i = 0; i < 4; i++)
      pk[i] = *(const f32x4*)(kqb + (size_t)(tbase + lt + krow0 + 8 * i) * 32 + kcol);
  };
  auto writelds = [&](int bi) {
    *(f32x4*)&u_s[bi][t * 8] = pu0;
    *(f32x4*)&u_s[bi][t * 8 + 4] = pu1;
    *(f32x4*)&dt_s[bi][t * 8] = pd0;
    *(f32x4*)&dt_s[bi][t * 8 + 4] = pd1;
    *(f32x4*)&sz_s[bi][t * 8] = ps0;
    *(f32x4*)&sz_s[bi][t * 8 + 4] = ps1;
    *(u16x8*)&gz_s[bi][t * 8] = pg;
#pragma unroll
    for (int i = 0; i < 4; i++)
      *(f32x4*)&kq_s[bi][krow0 + 8 * i][kcol] = pk[i];
  };
  size_t so = (((size_t)b * CCH + c) * D_INNER + db * 16 + dloc) * 16 + nq * 4;
  f32x4 v = *(const f32x4*)(gp + so);
  f32x4 h = *(const f32x4*)(rp + so);
  prefetch(0);
  writelds(0);
  int buf = 0;
  for (int t0 = 0; t0 < CLEN; t0 += 32) {
    const bool more = (t0 + 32 < CLEN);
    if (more) prefetch(t0 + 32);
#pragma unroll 4
    for (int s = 0; s < 32; s++) {
      float u = u_s[buf][s * 16 + dloc];
      float dtf = dt_s[buf][s * 16 + dloc];
      f32x4 kv = *(const f32x4*)&kq_s[buf][s][nq * 4];
      f32x4 qv = *(const f32x4*)&kq_s[buf][s][16 + nq * 4];
      float yp = 0.0f;
#pragma unroll
      for (int j = 0; j < 4; j++) {
        float kj = kv[j];
        v[j] = fmaf(0.9f, v[j], u * kj);
        float dA = fmaf(-dtf * kj, kj, 1.0f);
        h[j] = fmaf(dA, h[j], v[j]);
        yp = fmaf(h[j], qv[j], yp);
      }
      yp += __shfl_xor(yp, 1);
      yp += __shfl_xor(yp, 2);
      if (nq == 0) {
        float val = fmaf(yp, sz_s[buf][s * 16 + dloc], bfu(gz_s[buf][s * 16 + dloc]));
        y_p[(size_t)(tbase + t0 + s) * D_INNER] = f2bu(val);
      }
    }
    if (more) writelds(buf ^ 1);
    buf ^= 1;
  }
}

extern "C" void kernel_launch(void* const* d_in, const int* in_sizes, int n_in,
                              void* d_out, int out_size, void* d_ws, size_t ws_size,
                              hipStream_t stream) {
  const float* hidden = (const float*)d_in[0];
  const float* w_in   = (const float*)d_in[1];
  const float* conv_w = (const float*)d_in[2];
  const float* conv_b = (const float*)d_in[3];
  const float* w_x    = (const float*)d_in[4];
  const float* w_dt   = (const float*)d_in[5];
  const float* b_dt   = (const float*)d_in[6];
  const float* w_out  = (const float*)d_in[7];
  const float* Dp     = (const float*)d_in[8];

  float* ws    = (float*)d_ws;
  float* xz    = ws;                                  // 2048*3072
  float* xconv = xz + (size_t)NROWS * 3072;           // 2048*1536 (linear)
  float* xdbl  = xconv + (size_t)NROWS * D_INNER;     // 2048*80
  float* dtblk = xdbl + (size_t)NROWS * 80;           // 2048*1536 (BLOCKED)
  float* ublk  = dtblk + (size_t)NROWS * D_INNER;     // 2048*1536 (BLOCKED)
  float* kqbuf = ublk + (size_t)NROWS * D_INNER;      // 2048*32
  float* szblk = kqbuf + (size_t)NROWS * 32;          // 2048*1536 (BLOCKED, old ybuf slot)
  const size_t PL = (size_t)NB * CCH * D_INNER * 16;  // 393216 per plane
  float* cvp   = szblk + (size_t)NROWS * D_INNER;
  float* chp   = cvp + PL;
  float* gp    = chp + PL;
  float* rp    = gp + PL;
  unsigned short* bfr = (unsigned short*)(rp + PL);
  unsigned short* hbf = bfr;                          // 1572864 (also gzblk after in_proj)
  unsigned short* wib = hbf + 1572864;                // 2359296
  unsigned short* wxb = wib + 2359296;                // 122880
  unsigned short* wdb = wxb + 122880;                 // 73728
  unsigned short* wob = wdb + 73728;                  // 1179648
  unsigned short* xcb = wob + 1179648;                // 3145728
  unsigned short* ygb = xcb + 3145728;                // 3145728
  unsigned short* gzblk = hbf;  // 3145728 shorts, overlays hbf+wib (dead after in_proj)

  dim3 blk(256);
  // 0. cvt static operands to bf16 + zero xdbl/d_out
  cvt5z_kernel<<<dim3((CVT_TOTAL + Z1_GROUPS + Z2_GROUPS) / 256), blk, 0, stream>>>(
      hidden, w_in, w_x, w_dt, w_out, hbf, wib, wxb, wdb, wob, xdbl, (float*)d_out);
  // 1. in_proj: 128x128 tile (2048 x 3072, K=768) — last reader of hbf/wib
  gemm128<false><<<dim3(24, 16, 1), blk, 0, stream>>>(hbf, wib, xz, 768, 768, 768, 3072, 768);
  // 2. conv + SiLU; emits xc, xcb, sz(blocked), gz(blocked bf16, overlays hbf)
  conv_silu_kernel<<<dim3(12288), blk, 0, stream>>>(xz, conv_w, conv_b, Dp,
                                                    xconv, xcb, szblk, gzblk);
  // 3. x_proj: 64-tile split-K=8, atomic (2048 x 80, K=1536)
  gemm_bt<true><<<dim3(2, 32, 8), blk, 0, stream>>>(xcb, wxb, xdbl, 2048, 80, 1536,
                                                    1536, 1536, 80, 192);
  // 4. precompute (+ fused dt_head dot48); u/dt blocked
  precompute_kernel<<<dim3(NROWS), blk, 0, stream>>>(xdbl, wdb, xconv, b_dt, dtblk, ublk, kqbuf);
  // 5. segmented scan: ph1, ph2, ph3(+gate via sz/gz)
  scan_phase1<<<dim3(NB * 96 * CCH), dim3(64), 0, stream>>>(ublk, dtblk, kqbuf, cvp, chp, gp, rp);
  scan_phase2<<<dim3(192), blk, 0, stream>>>(cvp, chp, gp, rp);
  scan_phase3<<<dim3(NB * 96 * CCH), dim3(64), 0, stream>>>(ublk, dtblk, kqbuf, gp, rp,
                                                            szblk, gzblk, ygb);
  // 6. out_proj: 128x128 split-K=4, atomic -> FP32 d_out (2048 x 768, K=1536)
  gemm128<true><<<dim3(6, 16, 4), blk, 0, stream>>>(ygb, wob, (float*)d_out, 384,
                                                    1536, 1536, 768, 384);
}